// Round 3
// baseline (188.027 us; speedup 1.0000x reference)
//
#include <hip/hip_runtime.h>
#include <hip/hip_bf16.h>

typedef __attribute__((ext_vector_type(4))) float  float4v;
typedef __attribute__((ext_vector_type(4))) short  short4v;
typedef __attribute__((ext_vector_type(8))) short  short8v;
typedef __attribute__((ext_vector_type(8))) __bf16 bf16x8;

constexpr int E_NUM = 64;
constexpr int HID   = 64;    // expert hidden
constexpr int DIN   = 1024;
constexpr int DOUT  = 1024;
constexpr int TPE   = 1024;  // tokens per expert = 65536/64

__device__ __forceinline__ ushort bf16_rne(float f) {
  unsigned int u = __builtin_bit_cast(unsigned int, f);
  u += 0x7FFFu + ((u >> 16) & 1u);
  return (ushort)(u >> 16);
}

// ---------------------------------------------------------------------------
// Kernel 1: h[t, 0:64] = relu( x[t, :] @ W1[e]^T ), h stored bf16 in ws.
// Tile: BM=64 tokens x BN=64 (all H), K-loop over DIN in BK=64 steps.
// 4 waves; wave wv owns rows [wv*16, wv*16+16). grid = 64 experts * 16 = 1024.
// ---------------------------------------------------------------------------
__global__ __launch_bounds__(256) void fc1_relu_kernel(
    const float* __restrict__ x, const float* __restrict__ w1,
    ushort* __restrict__ hbuf) {
  constexpr int BM = 64, BK = 64;
  __shared__ ushort Xs[BM * BK];   // bf16 bits, XOR-swizzled
  __shared__ ushort Ws[HID * BK];

  // XCD-bijective swizzle: nwg=1024, divisible by 8 -> contiguous chunk/XCD
  int nwg = (int)gridDim.x;
  int blk = (int)(blockIdx.x & 7) * (nwg >> 3) + (int)(blockIdx.x >> 3);

  int e  = blk >> 4;        // 16 row-blocks per expert
  int rb = blk & 15;
  const float* xe = x  + (size_t)(e * TPE + rb * BM) * DIN;
  const float* we = w1 + (size_t)e * HID * DIN;

  int tid  = (int)threadIdx.x;
  int lane = tid & 63;
  int wv   = tid >> 6;

  float4v acc[4];
#pragma unroll
  for (int nf = 0; nf < 4; nf++)
#pragma unroll
    for (int j = 0; j < 4; j++) acc[nf][j] = 0.f;

  int ar = wv * 16 + (lane & 15);   // A-fragment row within tile
  int kg = (lane >> 4) * 8;         // fragment k-offset

  for (int kt = 0; kt < DIN; kt += BK) {
    // stage X tile: 64x64 fp32 -> bf16 (1024 float4 chunks / 256 threads)
#pragma unroll
    for (int i = 0; i < 4; i++) {
      int f = tid + i * 256;
      int row = f >> 4, c4 = f & 15;
      float4v v = *(const float4v*)(xe + (size_t)row * DIN + kt + c4 * 4);
      short4v b;
#pragma unroll
      for (int j = 0; j < 4; j++) b[j] = (short)bf16_rne(v[j]);
      *(short4v*)&Xs[(row * BK + c4 * 4) ^ ((row & 7) << 3)] = b;
    }
    // stage W1 tile: 64x64 fp32 -> bf16
#pragma unroll
    for (int i = 0; i < 4; i++) {
      int f = tid + i * 256;
      int row = f >> 4, c4 = f & 15;
      float4v v = *(const float4v*)(we + (size_t)row * DIN + kt + c4 * 4);
      short4v b;
#pragma unroll
      for (int j = 0; j < 4; j++) b[j] = (short)bf16_rne(v[j]);
      *(short4v*)&Ws[(row * BK + c4 * 4) ^ ((row & 7) << 3)] = b;
    }
    __syncthreads();
#pragma unroll
    for (int kk = 0; kk < BK; kk += 32) {
      int k0 = kk + kg;
      short8v a = *(const short8v*)&Xs[(ar * BK + k0) ^ ((ar & 7) << 3)];
#pragma unroll
      for (int nf = 0; nf < 4; nf++) {
        int br = nf * 16 + (lane & 15);
        short8v b = *(const short8v*)&Ws[(br * BK + k0) ^ ((br & 7) << 3)];
        acc[nf] = __builtin_amdgcn_mfma_f32_16x16x32_bf16(
            __builtin_bit_cast(bf16x8, a), __builtin_bit_cast(bf16x8, b),
            acc[nf], 0, 0, 0);
      }
    }
    __syncthreads();
  }

  // epilogue: relu + bf16 store. C/D layout: col=lane&15, row=(lane>>4)*4+j
  size_t r0 = (size_t)(e * TPE + rb * BM) + wv * 16 + ((lane >> 4) << 2);
#pragma unroll
  for (int nf = 0; nf < 4; nf++) {
    int col = nf * 16 + (lane & 15);
#pragma unroll
    for (int j = 0; j < 4; j++) {
      float v = fmaxf(acc[nf][j], 0.f);
      hbuf[(r0 + j) * HID + col] = bf16_rne(v);
    }
  }
}

// ---------------------------------------------------------------------------
// Kernel 2: y[t, o] = h[t, :] @ W2[e]^T. Single K=64 pass.
// Tile: BM=128 tokens x BN=128 outputs. 4 waves; wave owns 32 rows x 128 cols.
// grid = 64 experts * 8 * 8 = 4096.
// ---------------------------------------------------------------------------
__global__ __launch_bounds__(256) void fc2_kernel(
    const ushort* __restrict__ hbuf, const float* __restrict__ w2,
    float* __restrict__ y) {
  constexpr int BM = 128, BN = 128, K = 64;
  __shared__ ushort Hs[BM * K];
  __shared__ ushort Ws[BN * K];

  int nwg = (int)gridDim.x;  // 4096, divisible by 8
  int blk = (int)(blockIdx.x & 7) * (nwg >> 3) + (int)(blockIdx.x >> 3);

  int e  = blk >> 6;
  int mb = (blk >> 3) & 7;
  int nb = blk & 7;
  const ushort* he = hbuf + (size_t)(e * TPE + mb * BM) * K;
  const float*  we = w2 + ((size_t)e * DOUT + nb * BN) * K;

  int tid  = (int)threadIdx.x;
  int lane = tid & 63;
  int wv   = tid >> 6;

  // stage H: 128x64 bf16 (1024 chunks of 8 ushort = 16B each)
#pragma unroll
  for (int i = 0; i < 4; i++) {
    int f = tid + i * 256;
    int row = f >> 3, c8 = f & 7;
    short8v v = *(const short8v*)(he + (size_t)row * K + c8 * 8);
    *(short8v*)&Hs[(row * K + c8 * 8) ^ ((row & 7) << 3)] = v;
  }
  // stage W2: 128x64 fp32 -> bf16 (2048 float4 chunks)
#pragma unroll
  for (int i = 0; i < 8; i++) {
    int f = tid + i * 256;
    int row = f >> 4, c4 = f & 15;
    float4v v = *(const float4v*)(we + (size_t)row * K + c4 * 4);
    short4v b;
#pragma unroll
    for (int j = 0; j < 4; j++) b[j] = (short)bf16_rne(v[j]);
    *(short4v*)&Ws[(row * K + c4 * 4) ^ ((row & 7) << 3)] = b;
  }
  __syncthreads();

  float4v acc[2][8];
#pragma unroll
  for (int mf = 0; mf < 2; mf++)
#pragma unroll
    for (int nf = 0; nf < 8; nf++)
#pragma unroll
      for (int j = 0; j < 4; j++) acc[mf][nf][j] = 0.f;

  int kg = (lane >> 4) * 8;
#pragma unroll
  for (int kk = 0; kk < K; kk += 32) {
    int k0 = kk + kg;
    short8v a[2];
#pragma unroll
    for (int mf = 0; mf < 2; mf++) {
      int arr = wv * 32 + mf * 16 + (lane & 15);
      a[mf] = *(const short8v*)&Hs[(arr * K + k0) ^ ((arr & 7) << 3)];
    }
#pragma unroll
    for (int nf = 0; nf < 8; nf++) {
      int br = nf * 16 + (lane & 15);
      short8v b = *(const short8v*)&Ws[(br * K + k0) ^ ((br & 7) << 3)];
#pragma unroll
      for (int mf = 0; mf < 2; mf++)
        acc[mf][nf] = __builtin_amdgcn_mfma_f32_16x16x32_bf16(
            __builtin_bit_cast(bf16x8, a[mf]), __builtin_bit_cast(bf16x8, b),
            acc[mf][nf], 0, 0, 0);
    }
  }

  // epilogue: direct fp32 stores (16-lane x 64B row segments)
  size_t row0 = (size_t)(e * TPE + mb * BM) + wv * 32 + ((lane >> 4) << 2);
  int col0 = nb * BN + (lane & 15);
#pragma unroll
  for (int mf = 0; mf < 2; mf++) {
#pragma unroll
    for (int j = 0; j < 4; j++) {
      float* yr = y + (row0 + mf * 16 + j) * DOUT + col0;
#pragma unroll
      for (int nf = 0; nf < 8; nf++) yr[nf * 16] = acc[mf][nf][j];
    }
  }
}

extern "C" void kernel_launch(void* const* d_in, const int* in_sizes, int n_in,
                              void* d_out, int out_size, void* d_ws, size_t ws_size,
                              hipStream_t stream) {
  const float* x  = (const float*)d_in[0];
  // d_in[1] = fwd_expert_count: equal groups (T/E) by problem construction
  const float* w1 = (const float*)d_in[2];
  const float* w2 = (const float*)d_in[3];
  float* yout = (float*)d_out;
  ushort* hbuf = (ushort*)d_ws;   // T * 64 bf16 = 8.4 MB scratch

  fc1_relu_kernel<<<E_NUM * 16, 256, 0, stream>>>(x, w1, hbuf);
  fc2_kernel<<<E_NUM * 64, 256, 0, stream>>>(hbuf, w2, yout);
}

// Round 4
// 167.801 us; speedup vs baseline: 1.1205x; 1.1205x over previous
//
#include <hip/hip_runtime.h>
#include <hip/hip_bf16.h>

typedef __attribute__((ext_vector_type(4))) float  float4v;
typedef __attribute__((ext_vector_type(4))) short  short4v;
typedef __attribute__((ext_vector_type(8))) short  short8v;
typedef __attribute__((ext_vector_type(8))) __bf16 bf16x8;

constexpr int E_NUM = 64;
constexpr int HID   = 64;    // expert hidden
constexpr int DIN   = 1024;
constexpr int DOUT  = 1024;
constexpr int TPE   = 1024;  // tokens per expert = 65536/64

__device__ __forceinline__ short4v cvt4(float4v v) {
  short4v r;
#pragma unroll
  for (int j = 0; j < 4; j++) {
    __bf16 b = (__bf16)v[j];
    r[j] = __builtin_bit_cast(short, b);
  }
  return r;
}
__device__ __forceinline__ ushort cvt1(float f) {
  __bf16 b = (__bf16)f;
  return __builtin_bit_cast(ushort, b);
}

// ---------------------------------------------------------------------------
// Kernel 1: h[t, 0:64] = relu( x[t, :] @ W1[e]^T ), h stored bf16 in ws.
// BM=128 tokens x BN=64 (all HID). 512 threads (8 waves, 16 rows each).
// K-loop: reg-prefetch + double-buffered LDS, ONE barrier per K-step.
// grid = 64 experts * 8 = 512 blocks (2 blocks/CU).
// ---------------------------------------------------------------------------
__global__ __launch_bounds__(512, 4) void fc1_relu_kernel(
    const float* __restrict__ x, const float* __restrict__ w1,
    ushort* __restrict__ hbuf) {
  constexpr int BM = 128, BK = 64;
  __shared__ ushort Xs[2][BM * BK];   // bf16 bits, XOR-swizzled
  __shared__ ushort Ws[2][HID * BK];

  // XCD-bijective swizzle: nwg=512 (div by 8); expert's 8 blocks share an XCD
  int nwg = (int)gridDim.x;
  int blk = (int)(blockIdx.x & 7) * (nwg >> 3) + (int)(blockIdx.x >> 3);
  int e  = blk >> 3;
  int rb = blk & 7;
  const float* xe = x  + (size_t)(e * TPE + rb * BM) * DIN;
  const float* we = w1 + (size_t)e * HID * DIN;

  int tid  = (int)threadIdx.x;
  int lane = tid & 63;
  int wv   = tid >> 6;

  // staging chunk coords (16B fp32 chunks): X tile 128x64 = 2048 chunks,
  // W tile 64x64 = 1024 chunks, 512 threads.
  int xrow[4], xc4[4], wrow[2], wc4[2];
#pragma unroll
  for (int i = 0; i < 4; i++) { int f = tid + i * 512; xrow[i] = f >> 4; xc4[i] = f & 15; }
#pragma unroll
  for (int i = 0; i < 2; i++) { int f = tid + i * 512; wrow[i] = f >> 4; wc4[i] = f & 15; }

  float4v xr0[4], wr0[2], xr1[4], wr1[2];   // two named reg sets (rule #20)

  auto LOAD0 = [&](int kt) {
#pragma unroll
    for (int i = 0; i < 4; i++) xr0[i] = *(const float4v*)(xe + (size_t)xrow[i] * DIN + kt + xc4[i] * 4);
#pragma unroll
    for (int i = 0; i < 2; i++) wr0[i] = *(const float4v*)(we + (size_t)wrow[i] * DIN + kt + wc4[i] * 4);
  };
  auto LOAD1 = [&](int kt) {
#pragma unroll
    for (int i = 0; i < 4; i++) xr1[i] = *(const float4v*)(xe + (size_t)xrow[i] * DIN + kt + xc4[i] * 4);
#pragma unroll
    for (int i = 0; i < 2; i++) wr1[i] = *(const float4v*)(we + (size_t)wrow[i] * DIN + kt + wc4[i] * 4);
  };
  auto WRITE0 = [&]() {
#pragma unroll
    for (int i = 0; i < 4; i++)
      *(short4v*)&Xs[0][(xrow[i] * BK + xc4[i] * 4) ^ ((xrow[i] & 7) << 3)] = cvt4(xr0[i]);
#pragma unroll
    for (int i = 0; i < 2; i++)
      *(short4v*)&Ws[0][(wrow[i] * BK + wc4[i] * 4) ^ ((wrow[i] & 7) << 3)] = cvt4(wr0[i]);
  };
  auto WRITE1 = [&]() {
#pragma unroll
    for (int i = 0; i < 4; i++)
      *(short4v*)&Xs[1][(xrow[i] * BK + xc4[i] * 4) ^ ((xrow[i] & 7) << 3)] = cvt4(xr1[i]);
#pragma unroll
    for (int i = 0; i < 2; i++)
      *(short4v*)&Ws[1][(wrow[i] * BK + wc4[i] * 4) ^ ((wrow[i] & 7) << 3)] = cvt4(wr1[i]);
  };

  float4v acc[4];
#pragma unroll
  for (int nf = 0; nf < 4; nf++)
#pragma unroll
    for (int j = 0; j < 4; j++) acc[nf][j] = 0.f;

  int ar = wv * 16 + (lane & 15);
  int kg = (lane >> 4) * 8;

  auto MMA = [&](const ushort* Xb, const ushort* Wb) {
#pragma unroll
    for (int kk = 0; kk < BK; kk += 32) {
      int k0 = kk + kg;
      short8v a = *(const short8v*)&Xb[(ar * BK + k0) ^ ((ar & 7) << 3)];
#pragma unroll
      for (int nf = 0; nf < 4; nf++) {
        int br = nf * 16 + (lane & 15);
        short8v b = *(const short8v*)&Wb[(br * BK + k0) ^ ((br & 7) << 3)];
        acc[nf] = __builtin_amdgcn_mfma_f32_16x16x32_bf16(
            __builtin_bit_cast(bf16x8, a), __builtin_bit_cast(bf16x8, b),
            acc[nf], 0, 0, 0);
      }
    }
  };

  // ---- pipelined K loop: 16 steps as 8 x (phase0, phase1) ----
  LOAD0(0);
  for (int it2 = 0; it2 < 8; ++it2) {
    int kt = it2 * 2 * BK;
    // phase 0: tile kt (regs set0 -> LDS buf0)
    WRITE0();
    __syncthreads();
    LOAD1(kt + BK);          // prefetch kt+64 (always valid: max 896+64=960)
    MMA(Xs[0], Ws[0]);
    // phase 1: tile kt+64 (regs set1 -> LDS buf1)
    WRITE1();
    __syncthreads();
    if (it2 < 7) LOAD0(kt + 2 * BK);   // prefetch kt+128
    MMA(Xs[1], Ws[1]);
  }

  // ---- epilogue: relu -> LDS (linear) -> coalesced 16B stores ----
  // Safe to write Xs[0]: last read of buf0 was MMA in phase 0, and every wave
  // passed the phase-1 barrier (which follows that MMA in program order).
  ushort* hs = &Xs[0][0];   // 128x64 bf16 = 16KB
#pragma unroll
  for (int nf = 0; nf < 4; nf++) {
    int col = nf * 16 + (lane & 15);
#pragma unroll
    for (int j = 0; j < 4; j++) {
      int row = wv * 16 + ((lane >> 4) << 2) + j;
      hs[row * HID + col] = cvt1(fmaxf(acc[nf][j], 0.f));
    }
  }
  __syncthreads();
  size_t rowbase = (size_t)(e * TPE + rb * BM);
#pragma unroll
  for (int i = 0; i < 2; i++) {
    int chunk = tid + i * 512;          // 1024 chunks of 16B
    int row = chunk >> 3, c8 = (chunk & 7) * 8;
    short8v v = *(const short8v*)&hs[row * HID + c8];
    *(short8v*)(hbuf + (rowbase + row) * HID + c8) = v;
  }
}

// ---------------------------------------------------------------------------
// Kernel 2: y[t, o] = h[t, :] @ W2[e]^T. Single K=64 pass. (unchanged)
// Tile: BM=128 tokens x BN=128 outputs. 4 waves; wave owns 32 rows x 128 cols.
// grid = 64 experts * 8 * 8 = 4096.
// ---------------------------------------------------------------------------
__global__ __launch_bounds__(256) void fc2_kernel(
    const ushort* __restrict__ hbuf, const float* __restrict__ w2,
    float* __restrict__ y) {
  constexpr int BM = 128, BN = 128, K = 64;
  __shared__ ushort Hs[BM * K];
  __shared__ ushort Ws[BN * K];

  int nwg = (int)gridDim.x;  // 4096, divisible by 8
  int blk = (int)(blockIdx.x & 7) * (nwg >> 3) + (int)(blockIdx.x >> 3);

  int e  = blk >> 6;
  int mb = (blk >> 3) & 7;
  int nb = blk & 7;
  const ushort* he = hbuf + (size_t)(e * TPE + mb * BM) * K;
  const float*  we = w2 + ((size_t)e * DOUT + nb * BN) * K;

  int tid  = (int)threadIdx.x;
  int lane = tid & 63;
  int wv   = tid >> 6;

  // stage H: 128x64 bf16 (1024 chunks of 16B)
#pragma unroll
  for (int i = 0; i < 4; i++) {
    int f = tid + i * 256;
    int row = f >> 3, c8 = f & 7;
    short8v v = *(const short8v*)(he + (size_t)row * K + c8 * 8);
    *(short8v*)&Hs[(row * K + c8 * 8) ^ ((row & 7) << 3)] = v;
  }
  // stage W2: 128x64 fp32 -> bf16 (2048 float4 chunks)
#pragma unroll
  for (int i = 0; i < 8; i++) {
    int f = tid + i * 256;
    int row = f >> 4, c4 = f & 15;
    float4v v = *(const float4v*)(we + (size_t)row * K + c4 * 4);
    *(short4v*)&Ws[(row * K + c4 * 4) ^ ((row & 7) << 3)] = cvt4(v);
  }
  __syncthreads();

  float4v acc[2][8];
#pragma unroll
  for (int mf = 0; mf < 2; mf++)
#pragma unroll
    for (int nf = 0; nf < 8; nf++)
#pragma unroll
      for (int j = 0; j < 4; j++) acc[mf][nf][j] = 0.f;

  int kg = (lane >> 4) * 8;
#pragma unroll
  for (int kk = 0; kk < K; kk += 32) {
    int k0 = kk + kg;
    short8v a[2];
#pragma unroll
    for (int mf = 0; mf < 2; mf++) {
      int arr = wv * 32 + mf * 16 + (lane & 15);
      a[mf] = *(const short8v*)&Hs[(arr * K + k0) ^ ((arr & 7) << 3)];
    }
#pragma unroll
    for (int nf = 0; nf < 8; nf++) {
      int br = nf * 16 + (lane & 15);
      short8v b = *(const short8v*)&Ws[(br * K + k0) ^ ((br & 7) << 3)];
#pragma unroll
      for (int mf = 0; mf < 2; mf++)
        acc[mf][nf] = __builtin_amdgcn_mfma_f32_16x16x32_bf16(
            __builtin_bit_cast(bf16x8, a[mf]), __builtin_bit_cast(bf16x8, b),
            acc[mf][nf], 0, 0, 0);
    }
  }

  // epilogue: direct fp32 stores (16-lane x 64B row segments)
  size_t row0 = (size_t)(e * TPE + mb * BM) + wv * 32 + ((lane >> 4) << 2);
  int col0 = nb * BN + (lane & 15);
#pragma unroll
  for (int mf = 0; mf < 2; mf++) {
#pragma unroll
    for (int j = 0; j < 4; j++) {
      float* yr = y + (row0 + mf * 16 + j) * DOUT + col0;
#pragma unroll
      for (int nf = 0; nf < 8; nf++) yr[nf * 16] = acc[mf][nf][j];
    }
  }
}

extern "C" void kernel_launch(void* const* d_in, const int* in_sizes, int n_in,
                              void* d_out, int out_size, void* d_ws, size_t ws_size,
                              hipStream_t stream) {
  const float* x  = (const float*)d_in[0];
  // d_in[1] = fwd_expert_count: equal groups (T/E) by problem construction
  const float* w1 = (const float*)d_in[2];
  const float* w2 = (const float*)d_in[3];
  float* yout = (float*)d_out;
  ushort* hbuf = (ushort*)d_ws;   // T * 64 bf16 = 8.4 MB scratch

  fc1_relu_kernel<<<E_NUM * 8, 512, 0, stream>>>(x, w1, hbuf);
  fc2_kernel<<<E_NUM * 64, 256, 0, stream>>>(hbuf, w2, yout);
}

// Round 5
// 152.809 us; speedup vs baseline: 1.2305x; 1.0981x over previous
//
#include <hip/hip_runtime.h>
#include <hip/hip_bf16.h>

typedef __attribute__((ext_vector_type(4))) float  float4v;
typedef __attribute__((ext_vector_type(4))) short  short4v;
typedef __attribute__((ext_vector_type(8))) short  short8v;
typedef __attribute__((ext_vector_type(8))) __bf16 bf16x8;

constexpr int E_NUM = 64;
constexpr int HID   = 64;    // expert hidden
constexpr int DIN   = 1024;
constexpr int DOUT  = 1024;
constexpr int TPE   = 1024;  // tokens per expert = 65536/64

__device__ __forceinline__ short4v cvt4(float4v v) {
  short4v r;
#pragma unroll
  for (int j = 0; j < 4; j++) {
    __bf16 b = (__bf16)v[j];
    r[j] = __builtin_bit_cast(short, b);
  }
  return r;
}
__device__ __forceinline__ ushort cvt1(float f) {
  __bf16 b = (__bf16)f;
  return __builtin_bit_cast(ushort, b);
}

// ---------------------------------------------------------------------------
// Kernel 1: h[t, 0:64] = relu( x[t, :] @ W1[e]^T ), h stored bf16 in ws.
// BM=64 tokens x BN=64 (all HID), BK=256: each global_load_dwordx4 covers a
// full 1KB contiguous row-slice (64 lanes x 16B) -> DRAM-page-friendly runs.
// 512 threads (8 waves). Per K-step each wave stages 8 X-rows + 8 W-rows.
// Double-buffered LDS (128KB), single reg set, ONE barrier per K-step.
// grid = 64 experts * 16 = 1024 blocks (1 block/CU, 4 rounds).
// ---------------------------------------------------------------------------
__global__ __launch_bounds__(512, 2) void fc1_relu_kernel(
    const float* __restrict__ x, const float* __restrict__ w1,
    ushort* __restrict__ hbuf) {
  constexpr int BM = 64, BK = 256;
  __shared__ ushort Xs[2][BM * BK];   // 2 x 32KB, bf16 bits, XOR-swizzled
  __shared__ ushort Ws[2][HID * BK];  // 2 x 32KB

  // XCD-bijective swizzle: nwg=1024 (div by 8) -> expert's 16 blocks on 1 XCD
  int nwg = (int)gridDim.x;
  int blk = (int)(blockIdx.x & 7) * (nwg >> 3) + (int)(blockIdx.x >> 3);
  int e  = blk >> 4;
  int rb = blk & 15;
  const float* xe = x  + (size_t)(e * TPE + rb * BM) * DIN;
  const float* we = w1 + (size_t)e * HID * DIN;

  int tid  = (int)threadIdx.x;
  int lane = tid & 63;
  int wv   = tid >> 6;

  float4v xr[8], wr[8];   // single prefetch reg set (64 VGPR)

  auto LOAD = [&](int kt) {
#pragma unroll
    for (int i = 0; i < 8; i++) {
      int row = wv * 8 + i;   // one row per instruction: 1KB contiguous
      xr[i] = *(const float4v*)(xe + (size_t)row * DIN + kt + lane * 4);
      wr[i] = *(const float4v*)(we + (size_t)row * DIN + kt + lane * 4);
    }
  };
  auto WRITE = [&](ushort* Xb, ushort* Wb) {
#pragma unroll
    for (int i = 0; i < 8; i++) {
      int row = wv * 8 + i;                       // row & 7 == i (compile-time)
      int idx = (row * BK + lane * 4) ^ (i << 3); // XOR swizzle on 16B groups
      *(short4v*)&Xb[idx] = cvt4(xr[i]);
      *(short4v*)&Wb[idx] = cvt4(wr[i]);
    }
  };

  // wave -> output sub-tile: mf = wv>>1 (16-row group), nb2 = (wv&1)*2 (2 nfrags)
  int mf  = wv >> 1;
  int nb2 = (wv & 1) * 2;
  int ar  = mf * 16 + (lane & 15);
  int kg  = (lane >> 4) * 8;

  float4v acc[2];
#pragma unroll
  for (int j = 0; j < 2; j++)
#pragma unroll
    for (int jj = 0; jj < 4; jj++) acc[j][jj] = 0.f;

  auto MMA = [&](const ushort* Xb, const ushort* Wb) {
#pragma unroll
    for (int kk = 0; kk < BK; kk += 32) {
      int k0 = kk + kg;
      short8v a = *(const short8v*)&Xb[(ar * BK + k0) ^ ((ar & 7) << 3)];
#pragma unroll
      for (int j = 0; j < 2; j++) {
        int br = (nb2 + j) * 16 + (lane & 15);
        short8v b = *(const short8v*)&Wb[(br * BK + k0) ^ ((br & 7) << 3)];
        acc[j] = __builtin_amdgcn_mfma_f32_16x16x32_bf16(
            __builtin_bit_cast(bf16x8, a), __builtin_bit_cast(bf16x8, b),
            acc[j], 0, 0, 0);
      }
    }
  };

  // ---- K loop: 4 steps, dbuf LDS, 1 barrier/step ----
  LOAD(0);
#pragma unroll
  for (int s = 0; s < 4; s++) {
    int buf = s & 1;
    WRITE(Xs[buf], Ws[buf]);        // consumes reg set (waits its loads)
    __syncthreads();
    if (s < 3) LOAD((s + 1) * BK);  // refill; stays in flight across MMA
    MMA(Xs[buf], Ws[buf]);
  }

  // ---- epilogue: relu -> LDS (linear) -> coalesced 16B contiguous stores ----
  // Xs[0] safe: last read of buf0 was MMA(s=2); every wave passed bar(s=3),
  // which follows its MMA(s=2) in program order.
  ushort* hs = &Xs[0][0];   // 64x64 bf16 = 8KB
#pragma unroll
  for (int j = 0; j < 2; j++) {
    int col = (nb2 + j) * 16 + (lane & 15);
#pragma unroll
    for (int jj = 0; jj < 4; jj++) {
      int row = mf * 16 + ((lane >> 4) << 2) + jj;
      hs[row * HID + col] = cvt1(fmaxf(acc[j][jj], 0.f));
    }
  }
  __syncthreads();
  size_t rowbase = (size_t)(e * TPE + rb * BM);
  int row = tid >> 3, c8 = (tid & 7) * 8;   // 512 threads x 16B = 8KB
  short8v v = *(const short8v*)&hs[row * HID + c8];
  *(short8v*)(hbuf + (rowbase + row) * HID + c8) = v;
}

// ---------------------------------------------------------------------------
// Kernel 2: y[t, o] = h[t, :] @ W2[e]^T. Single K=64 pass. (unchanged)
// Tile: BM=128 tokens x BN=128 outputs. 4 waves; wave owns 32 rows x 128 cols.
// grid = 64 experts * 8 * 8 = 4096.
// ---------------------------------------------------------------------------
__global__ __launch_bounds__(256) void fc2_kernel(
    const ushort* __restrict__ hbuf, const float* __restrict__ w2,
    float* __restrict__ y) {
  constexpr int BM = 128, BN = 128, K = 64;
  __shared__ ushort Hs[BM * K];
  __shared__ ushort Ws[BN * K];

  int nwg = (int)gridDim.x;  // 4096, divisible by 8
  int blk = (int)(blockIdx.x & 7) * (nwg >> 3) + (int)(blockIdx.x >> 3);

  int e  = blk >> 6;
  int mb = (blk >> 3) & 7;
  int nb = blk & 7;
  const ushort* he = hbuf + (size_t)(e * TPE + mb * BM) * K;
  const float*  we = w2 + ((size_t)e * DOUT + nb * BN) * K;

  int tid  = (int)threadIdx.x;
  int lane = tid & 63;
  int wv   = tid >> 6;

  // stage H: 128x64 bf16 (1024 chunks of 16B, fully contiguous region)
#pragma unroll
  for (int i = 0; i < 4; i++) {
    int f = tid + i * 256;
    int row = f >> 3, c8 = f & 7;
    short8v v = *(const short8v*)(he + (size_t)row * K + c8 * 8);
    *(short8v*)&Hs[(row * K + c8 * 8) ^ ((row & 7) << 3)] = v;
  }
  // stage W2: 128x64 fp32 -> bf16 (2048 float4 chunks, contiguous region)
#pragma unroll
  for (int i = 0; i < 8; i++) {
    int f = tid + i * 256;
    int row = f >> 4, c4 = f & 15;
    float4v v = *(const float4v*)(we + (size_t)row * K + c4 * 4);
    *(short4v*)&Ws[(row * K + c4 * 4) ^ ((row & 7) << 3)] = cvt4(v);
  }
  __syncthreads();

  float4v acc[2][8];
#pragma unroll
  for (int mf = 0; mf < 2; mf++)
#pragma unroll
    for (int nf = 0; nf < 8; nf++)
#pragma unroll
      for (int j = 0; j < 4; j++) acc[mf][nf][j] = 0.f;

  int kg = (lane >> 4) * 8;
#pragma unroll
  for (int kk = 0; kk < K; kk += 32) {
    int k0 = kk + kg;
    short8v a[2];
#pragma unroll
    for (int mf = 0; mf < 2; mf++) {
      int arr = wv * 32 + mf * 16 + (lane & 15);
      a[mf] = *(const short8v*)&Hs[(arr * K + k0) ^ ((arr & 7) << 3)];
    }
#pragma unroll
    for (int nf = 0; nf < 8; nf++) {
      int br = nf * 16 + (lane & 15);
      short8v b = *(const short8v*)&Ws[(br * K + k0) ^ ((br & 7) << 3)];
#pragma unroll
      for (int mf = 0; mf < 2; mf++)
        acc[mf][nf] = __builtin_amdgcn_mfma_f32_16x16x32_bf16(
            __builtin_bit_cast(bf16x8, a[mf]), __builtin_bit_cast(bf16x8, b),
            acc[mf][nf], 0, 0, 0);
    }
  }

  // epilogue: direct fp32 stores (per row, nf-unrolled -> 512B dense per row)
  size_t row0 = (size_t)(e * TPE + mb * BM) + wv * 32 + ((lane >> 4) << 2);
  int col0 = nb * BN + (lane & 15);
#pragma unroll
  for (int mf = 0; mf < 2; mf++) {
#pragma unroll
    for (int j = 0; j < 4; j++) {
      float* yr = y + (row0 + mf * 16 + j) * DOUT + col0;
#pragma unroll
      for (int nf = 0; nf < 8; nf++) yr[nf * 16] = acc[mf][nf][j];
    }
  }
}

extern "C" void kernel_launch(void* const* d_in, const int* in_sizes, int n_in,
                              void* d_out, int out_size, void* d_ws, size_t ws_size,
                              hipStream_t stream) {
  const float* x  = (const float*)d_in[0];
  // d_in[1] = fwd_expert_count: equal groups (T/E) by problem construction
  const float* w1 = (const float*)d_in[2];
  const float* w2 = (const float*)d_in[3];
  float* yout = (float*)d_out;
  ushort* hbuf = (ushort*)d_ws;   // T * 64 bf16 = 8.4 MB scratch

  fc1_relu_kernel<<<E_NUM * 16, 512, 0, stream>>>(x, w1, hbuf);
  fc2_kernel<<<E_NUM * 64, 256, 0, stream>>>(hbuf, w2, yout);
}